// Round 13
// baseline (361.623 us; speedup 1.0000x reference)
//
#include <hip/hip_runtime.h>
#include <hip/hip_bf16.h>

// Problem constants (fixed by the reference)
#define T_  2048
#define D_  1024
#define FF_ 512
#define E_  16
#define K_  4
#define L_  3
static constexpr float EPS = 1e-5f;

typedef __hip_bfloat16 bf16;
typedef __attribute__((ext_vector_type(8))) short bf16x8;   // MFMA A/B frag (4 VGPRs)
typedef __attribute__((ext_vector_type(4))) float f32x4;    // MFMA C/D frag

__device__ __forceinline__ float b2f(bf16 x) { return __bfloat162float(x); }

__device__ __forceinline__ unsigned int pk2(float a, float b) {
    __hip_bfloat162 h = __float22bfloat162_rn(make_float2(a, b));
    unsigned int u; __builtin_memcpy(&u, &h, 4); return u;
}

// async global->LDS, 16B per lane. Dest must be wave-uniform base; HW writes base + lane*16.
__device__ __forceinline__ void gload_lds16(const bf16* g, bf16* l) {
    __builtin_amdgcn_global_load_lds(
        (const __attribute__((address_space(1))) unsigned int*)g,
        (__attribute__((address_space(3))) unsigned int*)l, 16, 0, 0);
}

// split f32x4 into bf16 hi + bf16 lo packed pairs (hi+lo ~ f32 precision)
__device__ __forceinline__ void split_pack(float4 v, uint2 &hi, uint2 &lo) {
    __hip_bfloat162 h01 = __float22bfloat162_rn(make_float2(v.x, v.y));
    __hip_bfloat162 h23 = __float22bfloat162_rn(make_float2(v.z, v.w));
    float2 r01 = make_float2(v.x - __bfloat162float(h01.x), v.y - __bfloat162float(h01.y));
    float2 r23 = make_float2(v.z - __bfloat162float(h23.x), v.w - __bfloat162float(h23.y));
    __hip_bfloat162 l01 = __float22bfloat162_rn(r01);
    __hip_bfloat162 l23 = __float22bfloat162_rn(r23);
    __builtin_memcpy(&hi.x, &h01, 4); __builtin_memcpy(&hi.y, &h23, 4);
    __builtin_memcpy(&lo.x, &l01, 4); __builtin_memcpy(&lo.y, &l23, 4);
}

// ================= weight pre-conversion (one memory-bound pass) =================
// 8 f32 per thread: 2x float4 loads (32B/lane) -> uint4 stores (16B/lane = coalescing
// sweet spot). All region sizes are multiples of 8 so chunks never straddle regions.
__global__ __launch_bounds__(256) void k_convert(const float* __restrict__ w1,
                                                 const float* __restrict__ w2,
                                                 const float* __restrict__ ipw,
                                                 const float* __restrict__ opw,
                                                 bf16* __restrict__ w1b,
                                                 bf16* __restrict__ w2b,
                                                 bf16* __restrict__ iph,
                                                 bf16* __restrict__ ipl,
                                                 bf16* __restrict__ oph,
                                                 bf16* __restrict__ opl) {
    const size_t n1 = (size_t)E_ * 2 * FF_ * D_;   // 16M
    const size_t n2 = (size_t)E_ * D_ * FF_;       // 8M
    const size_t n3 = (size_t)3 * D_ * D_;         // 3M
    const size_t n4 = (size_t)D_ * D_;             // 1M
    size_t i = ((size_t)blockIdx.x * 256 + threadIdx.x) * 8;
    if (i < n1) {
        float4 a = *(const float4*)&w1[i];
        float4 b = *(const float4*)&w1[i + 4];
        uint4 h; h.x = pk2(a.x, a.y); h.y = pk2(a.z, a.w);
        h.z = pk2(b.x, b.y); h.w = pk2(b.z, b.w);
        *(uint4*)&w1b[i] = h;
    } else if (i < n1 + n2) {
        size_t j = i - n1;
        float4 a = *(const float4*)&w2[j];
        float4 b = *(const float4*)&w2[j + 4];
        uint4 h; h.x = pk2(a.x, a.y); h.y = pk2(a.z, a.w);
        h.z = pk2(b.x, b.y); h.w = pk2(b.z, b.w);
        *(uint4*)&w2b[j] = h;
    } else if (i < n1 + n2 + n3) {
        size_t j = i - n1 - n2;
        float4 a = *(const float4*)&ipw[j];
        float4 b = *(const float4*)&ipw[j + 4];
        uint2 h0, l0, h1, l1;
        split_pack(a, h0, l0); split_pack(b, h1, l1);
        uint4 hh = make_uint4(h0.x, h0.y, h1.x, h1.y);
        uint4 ll = make_uint4(l0.x, l0.y, l1.x, l1.y);
        *(uint4*)&iph[j] = hh;
        *(uint4*)&ipl[j] = ll;
    } else if (i < n1 + n2 + n3 + n4) {
        size_t j = i - n1 - n2 - n3;
        float4 a = *(const float4*)&opw[j];
        float4 b = *(const float4*)&opw[j + 4];
        uint2 h0, l0, h1, l1;
        split_pack(a, h0, l0); split_pack(b, h1, l1);
        uint4 hh = make_uint4(h0.x, h0.y, h1.x, h1.y);
        uint4 ll = make_uint4(l0.x, l0.y, l1.x, l1.y);
        *(uint4*)&oph[j] = hh;
        *(uint4*)&opl[j] = ll;
    }
}

// ---------------- block reduction ----------------
__device__ __forceinline__ float blockReduceSum(float v) {
    #pragma unroll
    for (int off = 32; off > 0; off >>= 1) v += __shfl_down(v, off, 64);
    __shared__ float s[4];
    __shared__ float tot;
    int lane = threadIdx.x & 63, wid = threadIdx.x >> 6;
    if (lane == 0) s[wid] = v;
    __syncthreads();
    if (threadIdx.x == 0) tot = s[0] + s[1] + s[2] + s[3];
    __syncthreads();
    return tot;
}

// ---------------- addnorm1 + zero out0 (fused) ----------------
__global__ __launch_bounds__(256) void k_addnorm1z(const float* __restrict__ x,
                                                   const float* __restrict__ r,
                                                   const float* __restrict__ w,
                                                   bf16* __restrict__ hhi,
                                                   bf16* __restrict__ hlo,
                                                   float* __restrict__ res,
                                                   float* __restrict__ out0) {
    int t = blockIdx.x, tid = threadIdx.x;
    float v[4]; float ss = 0.f;
    #pragma unroll
    for (int i = 0; i < 4; i++) {
        int d = tid + 256 * i;
        float s = x[(size_t)t * D_ + d] + r[(size_t)t * D_ + d];
        v[i] = s; ss += s * s;
        out0[(size_t)t * D_ + d] = 0.f;           // zero MoE accumulator (fused)
    }
    float tot = blockReduceSum(ss);
    float rs = rsqrtf(tot / (float)D_ + EPS);
    #pragma unroll
    for (int i = 0; i < 4; i++) {
        int d = tid + 256 * i;
        res[(size_t)t * D_ + d] = v[i];
        float val = v[i] * rs * w[d];
        bf16 hi = __float2bfloat16(val);
        hhi[(size_t)t * D_ + d] = hi;
        hlo[(size_t)t * D_ + d] = __float2bfloat16(val - b2f(hi));
    }
}

// ======== split-precision MFMA GEMM, 64xTN tiles, BK=64 K-step (round-12 verified) ========
template<int TN>
__global__ __launch_bounds__(256) void k_gemm_small(const bf16* __restrict__ Ah,
                                                    const bf16* __restrict__ Al,
                                                    const bf16* __restrict__ Bh,
                                                    const bf16* __restrict__ Bl,
                                                    float* __restrict__ C,
                                                    int M, int N, int K) {
    constexpr int NF  = TN / 64;         // B frags per wave (16-wide each)
    constexpr int NBG = TN / 32;         // B staging row-groups (32 rows each)
    __shared__ bf16 Ash[64 * 64];
    __shared__ bf16 Asl[64 * 64];
    __shared__ bf16 Bsh[TN * 64];
    __shared__ bf16 Bsl[TN * 64];
    int m0 = blockIdx.y * 64, n0 = blockIdx.x * TN;
    int tid = threadIdx.x;
    int wave = tid >> 6, lane = tid & 63, ml = lane & 15, quad = lane >> 4;
    int wn = wave * (TN / 4);
    // staging: thread handles chunk g*256+tid (row g*32 + tid>>3, phys chunk tid&7)
    int r0 = tid >> 3, q0 = tid & 7;
    const bf16 *sAh[2], *sAl[2];
    #pragma unroll
    for (int g = 0; g < 2; g++) {
        int ra = g * 32 + r0;
        int c = (q0 ^ (ra & 7)) << 3;                 // pre-swizzled source column
        sAh[g] = Ah + (size_t)(m0 + ra) * K + c;
        sAl[g] = Al + (size_t)(m0 + ra) * K + c;
    }
    const bf16 *sBh[NBG], *sBl[NBG];
    #pragma unroll
    for (int g = 0; g < NBG; g++) {
        int rb = g * 32 + r0;
        int c = (q0 ^ (rb & 7)) << 3;
        sBh[g] = Bh + (size_t)(n0 + rb) * K + c;
        sBl[g] = Bl + (size_t)(n0 + rb) * K + c;
    }
    int offA[2][4], offB[2][NF];
    #pragma unroll
    for (int ks = 0; ks < 2; ks++) {
        int cq = ks * 4 + quad;                       // logical chunk for this k-subtile
        #pragma unroll
        for (int i = 0; i < 4; i++) {
            int ra = i * 16 + ml;
            offA[ks][i] = ra * 64 + ((cq ^ (ra & 7)) << 3);
        }
        #pragma unroll
        for (int j = 0; j < NF; j++) {
            int rb = wn + j * 16 + ml;
            offB[ks][j] = rb * 64 + ((cq ^ (rb & 7)) << 3);
        }
    }
    f32x4 acc[4][NF] = {};
    for (int kt = 0; kt < K; kt += 64) {
        #pragma unroll
        for (int g = 0; g < 2; g++) {
            gload_lds16(sAh[g] + kt, Ash + g * 2048 + wave * 512);
            gload_lds16(sAl[g] + kt, Asl + g * 2048 + wave * 512);
        }
        #pragma unroll
        for (int g = 0; g < NBG; g++) {
            gload_lds16(sBh[g] + kt, Bsh + g * 2048 + wave * 512);
            gload_lds16(sBl[g] + kt, Bsl + g * 2048 + wave * 512);
        }
        __syncthreads();
        #pragma unroll
        for (int ks = 0; ks < 2; ks++) {
            bf16x8 ah[4], al[4], bh[NF], bl[NF];
            #pragma unroll
            for (int i = 0; i < 4; i++) {
                ah[i] = *(const bf16x8*)&Ash[offA[ks][i]];
                al[i] = *(const bf16x8*)&Asl[offA[ks][i]];
            }
            #pragma unroll
            for (int j = 0; j < NF; j++) {
                bh[j] = *(const bf16x8*)&Bsh[offB[ks][j]];
                bl[j] = *(const bf16x8*)&Bsl[offB[ks][j]];
            }
            #pragma unroll
            for (int i = 0; i < 4; i++)
                #pragma unroll
                for (int j = 0; j < NF; j++) {
                    acc[i][j] = __builtin_amdgcn_mfma_f32_16x16x32_bf16(ah[i], bh[j], acc[i][j], 0, 0, 0);
                    acc[i][j] = __builtin_amdgcn_mfma_f32_16x16x32_bf16(al[i], bh[j], acc[i][j], 0, 0, 0);
                    acc[i][j] = __builtin_amdgcn_mfma_f32_16x16x32_bf16(ah[i], bl[j], acc[i][j], 0, 0, 0);
                }
        }
        __syncthreads();
    }
    #pragma unroll
    for (int i = 0; i < 4; i++)
        #pragma unroll
        for (int j = 0; j < NF; j++)
            #pragma unroll
            for (int r = 0; r < 4; r++) {
                int row = m0 + i * 16 + quad * 4 + r;        // C/D: row = quad*4+reg
                int col = n0 + wn + j * 16 + ml;             //      col = lane&15
                C[(size_t)row * N + col] = acc[i][j][r];
            }
}

// ---- fallback (f32 B, in-block split) — round-7 verified ----
__global__ __launch_bounds__(256) void k_gemm_split(const bf16* __restrict__ Ah,
                                                    const bf16* __restrict__ Al,
                                                    const float* __restrict__ B,
                                                    float* __restrict__ C,
                                                    int M, int N, int K) {
    __shared__ bf16 Ash[128][40];
    __shared__ bf16 Asl[128][40];
    __shared__ bf16 Bsh[128][40];
    __shared__ bf16 Bsl[128][40];
    int m0 = blockIdx.y * 128, n0 = blockIdx.x * 128;
    int tid = threadIdx.x;
    int wave = tid >> 6, lane = tid & 63, ml = lane & 15, quad = lane >> 4;
    int wm = (wave >> 1) * 64, wn = (wave & 1) * 64;
    f32x4 acc[4][4] = {};
    for (int kt = 0; kt < K; kt += 32) {
        #pragma unroll
        for (int p = 0; p < 2; p++) {
            int ch = p * 256 + tid, row = ch >> 2, c8 = (ch & 3) << 3;
            *(uint4*)&Ash[row][c8] = *(const uint4*)&Ah[(size_t)(m0 + row) * K + kt + c8];
            *(uint4*)&Asl[row][c8] = *(const uint4*)&Al[(size_t)(m0 + row) * K + kt + c8];
        }
        #pragma unroll
        for (int p = 0; p < 4; p++) {
            int ch = p * 256 + tid, row = ch >> 3, c4 = (ch & 7) << 2;
            float4 v = *(const float4*)&B[(size_t)(n0 + row) * K + kt + c4];
            uint2 hi, lo; split_pack(v, hi, lo);
            *(uint2*)&Bsh[row][c4] = hi;
            *(uint2*)&Bsl[row][c4] = lo;
        }
        __syncthreads();
        bf16x8 ah[4], al[4], bh[4], bl[4];
        #pragma unroll
        for (int i = 0; i < 4; i++) {
            ah[i] = *(const bf16x8*)&Ash[wm + i * 16 + ml][quad * 8];
            al[i] = *(const bf16x8*)&Asl[wm + i * 16 + ml][quad * 8];
        }
        #pragma unroll
        for (int j = 0; j < 4; j++) {
            bh[j] = *(const bf16x8*)&Bsh[wn + j * 16 + ml][quad * 8];
            bl[j] = *(const bf16x8*)&Bsl[wn + j * 16 + ml][quad * 8];
        }
        #pragma unroll
        for (int i = 0; i < 4; i++)
            #pragma unroll
            for (int j = 0; j < 4; j++) {
                acc[i][j] = __builtin_amdgcn_mfma_f32_16x16x32_bf16(ah[i], bh[j], acc[i][j], 0, 0, 0);
                acc[i][j] = __builtin_amdgcn_mfma_f32_16x16x32_bf16(al[i], bh[j], acc[i][j], 0, 0, 0);
                acc[i][j] = __builtin_amdgcn_mfma_f32_16x16x32_bf16(ah[i], bl[j], acc[i][j], 0, 0, 0);
            }
        __syncthreads();
    }
    #pragma unroll
    for (int i = 0; i < 4; i++)
        #pragma unroll
        for (int j = 0; j < 4; j++)
            #pragma unroll
            for (int r = 0; r < 4; r++) {
                int row = m0 + wm + i * 16 + quad * 4 + r;
                int col = n0 + wn + j * 16 + ml;
                C[(size_t)row * N + col] = acc[i][j][r];
            }
}

// ---------------- conv (+ zero cnt/done control block, fused) ----------------
__global__ __launch_bounds__(256) void k_conv2(const float* __restrict__ bcx,
                                               const float* __restrict__ cw,
                                               bf16* __restrict__ cchi,
                                               bf16* __restrict__ cclo,
                                               int* __restrict__ zctl) {
    int t = blockIdx.x, tid = threadIdx.x;
    if (blockIdx.x == 0 && tid < 32) zctl[tid] = 0;   // cnt[0..15] + done slot
    #pragma unroll
    for (int i = 0; i < 4; i++) {
        int d = tid + 256 * i;
        float acc = 0.f;
        #pragma unroll
        for (int l = 0; l < L_; l++) {
            int tt = t + l - (L_ - 1);
            if (tt >= 0) {
                float bb = bcx[(size_t)tt * 3 * D_ + d];
                float xx = bcx[(size_t)tt * 3 * D_ + 2 * D_ + d];
                acc += bb * xx * cw[d * L_ + l];
            }
        }
        float c = bcx[(size_t)t * 3 * D_ + D_ + d];
        float val = c * acc;
        bf16 hi = __float2bfloat16(val);
        cchi[(size_t)t * D_ + d] = hi;
        cclo[(size_t)t * D_ + d] = __float2bfloat16(val - b2f(hi));
    }
}

// ---------------- addnorm2 + gate (fused; h2 f32 never materialized) ----------------
__global__ __launch_bounds__(256) void k_an2_gate(const float* __restrict__ y,
                                                  float* __restrict__ res,
                                                  const float* __restrict__ w,
                                                  bf16* __restrict__ h2b,
                                                  const float* __restrict__ gw,
                                                  const float* __restrict__ gb,
                                                  int4* __restrict__ choice_idx,
                                                  float4* __restrict__ choice_wgt) {
    int t = blockIdx.x, tid = threadIdx.x;
    __shared__ float hs[D_];
    __shared__ float logits[E_];
    float v[4]; float ss = 0.f;
    #pragma unroll
    for (int i = 0; i < 4; i++) {
        int d = tid + 256 * i;
        float s = y[(size_t)t * D_ + d] + res[(size_t)t * D_ + d];
        v[i] = s; ss += s * s;
    }
    float tot = blockReduceSum(ss);
    float rs = rsqrtf(tot / (float)D_ + EPS);
    #pragma unroll
    for (int i = 0; i < 4; i++) {
        int d = tid + 256 * i;
        res[(size_t)t * D_ + d] = v[i];
        float val = v[i] * rs * w[d];
        h2b[(size_t)t * D_ + d] = __float2bfloat16(val);
        hs[d] = val;
    }
    __syncthreads();
    int e = tid >> 4, j = tid & 15;
    float p = 0.f;
    for (int d = j; d < D_; d += 16) p += hs[d] * gw[(size_t)e * D_ + d];
    #pragma unroll
    for (int off = 8; off > 0; off >>= 1) p += __shfl_down(p, off, 64);
    if (j == 0) logits[e] = p;
    __syncthreads();
    if (tid == 0) {
        float sc[E_], ch[E_];
        #pragma unroll
        for (int i = 0; i < E_; i++) {
            float s = 1.f / (1.f + expf(-logits[i]));
            sc[i] = s; ch[i] = s + gb[i];
        }
        int idx[K_]; float wv[K_]; float wsum = 0.f;
        bool used[E_] = {};
        #pragma unroll
        for (int k = 0; k < K_; k++) {
            int best = 0; float bv = -1e30f;
            for (int i = 0; i < E_; i++)
                if (!used[i] && ch[i] > bv) { bv = ch[i]; best = i; }
            used[best] = true; idx[k] = best; wv[k] = sc[best]; wsum += sc[best];
        }
        float inv = 1.f / (wsum + 1e-20f);
        choice_idx[t] = make_int4(idx[0], idx[1], idx[2], idx[3]);
        choice_wgt[t] = make_float4(wv[0] * inv, wv[1] * inv, wv[2] * inv, wv[3] * inv);
    }
}

// ---------------- scatter + last-block scan (fused) ----------------
__global__ __launch_bounds__(256) void k_scatter2(const int4* __restrict__ choice_idx,
                                                  const float4* __restrict__ choice_wgt,
                                                  int* __restrict__ cnt,
                                                  int* __restrict__ tok_list,
                                                  float* __restrict__ tok_w,
                                                  int* __restrict__ off,
                                                  int* __restrict__ done) {
    int e = blockIdx.x;
    __shared__ int ctr;
    if (threadIdx.x == 0) ctr = 0;
    __syncthreads();
    int lane = threadIdx.x & 63;
    for (int t = threadIdx.x; t < T_; t += 256) {
        int4   ci = choice_idx[t];
        float4 cw = choice_wgt[t];
        bool m = false; float w = 0.f;
        if (ci.x == e) { m = true; w = cw.x; }
        else if (ci.y == e) { m = true; w = cw.y; }
        else if (ci.z == e) { m = true; w = cw.z; }
        else if (ci.w == e) { m = true; w = cw.w; }
        unsigned long long mask = __ballot(m);
        int loff = __popcll(mask & ((1ull << lane) - 1ull));
        int wcnt = __popcll(mask);
        int base = 0;
        if (lane == 0 && wcnt > 0) base = atomicAdd(&ctr, wcnt);
        base = __shfl(base, 0, 64);
        if (m) {
            tok_list[e * T_ + base + loff] = t;
            tok_w[e * T_ + base + loff]    = w;
        }
    }
    __syncthreads();
    if (threadIdx.x == 0) {
        atomicExch(&cnt[e], ctr);          // device-scope publish
        __threadfence();
        int prev = atomicAdd(done, 1);
        if (prev == E_ - 1) {              // last block does the scan
            int s = 0;
            for (int i = 0; i < E_; i++) {
                int c = atomicAdd(&cnt[i], 0);   // device-scope read
                off[i] = s; s += min(c, T_);
            }
            off[E_] = s;
        }
    }
}

// ======== MoE w1 (MFMA), 64-token tiles, BK=64 K-step (round-11 verified) ========
__global__ __launch_bounds__(256) void k_moe_w1_pre(const bf16* __restrict__ h2,
                                                    const bf16* __restrict__ w1b,
                                                    const int* __restrict__ cnt,
                                                    const int* __restrict__ off,
                                                    const int* __restrict__ tok_list,
                                                    bf16* __restrict__ act) {
    int e = blockIdx.y >> 5, mt = blockIdx.y & 31;   // T/64 = 32 m-tiles
    int m0 = mt * 64;
    int nt = min(cnt[e], T_);
    if (m0 >= nt) return;
    int n0 = blockIdx.x * 64;
    int base = off[e];
    __shared__ bf16 As[64 * 64];
    __shared__ bf16 Bg[64 * 64];
    __shared__ bf16 Bu[64 * 64];
    int tid = threadIdx.x;
    int wave = tid >> 6, lane = tid & 63, ml = lane & 15, quad = lane >> 4;
    const bf16* w1e = w1b + (size_t)e * 2 * FF_ * D_;
    int r0 = tid >> 3, q0 = tid & 7;
    int r1 = 32 + r0;
    int c0 = (q0 ^ (r0 & 7)) << 3;
    int c1 = (q0 ^ (r1 & 7)) << 3;
    int ma0 = m0 + r0, ma1 = m0 + r1;
    int tok0 = tok_list[e * T_ + (ma0 < nt ? ma0 : 0)] & (T_ - 1);
    int tok1 = tok_list[e * T_ + (ma1 < nt ? ma1 : 0)] & (T_ - 1);
    const bf16* sA0  = h2 + (size_t)tok0 * D_ + c0;
    const bf16* sA1  = h2 + (size_t)tok1 * D_ + c1;
    const bf16* sBg0 = w1e + (size_t)(n0 + r0) * D_ + c0;
    const bf16* sBg1 = w1e + (size_t)(n0 + r1) * D_ + c1;
    const bf16* sBu0 = w1e + (size_t)(FF_ + n0 + r0) * D_ + c0;
    const bf16* sBu1 = w1e + (size_t)(FF_ + n0 + r1) * D_ + c1;
    int dst0 = wave * 512, dst1 = 2048 + wave * 512;   // elem offsets
    int offA[2], offB[2][4];
    #pragma unroll
    for (int ks = 0; ks < 2; ks++) {
        int ra = wave * 16 + ml;
        int cqa = ks * 4 + quad;
        offA[ks] = ra * 64 + ((cqa ^ (ra & 7)) << 3);
        #pragma unroll
        for (int j = 0; j < 4; j++) {
            int rb = j * 16 + ml;
            offB[ks][j] = rb * 64 + ((cqa ^ (rb & 7)) << 3);
        }
    }
    f32x4 ag[4] = {}, au[4] = {};
    for (int kt = 0; kt < D_; kt += 64) {
        gload_lds16(sA0 + kt,  As + dst0);
        gload_lds16(sA1 + kt,  As + dst1);
        gload_lds16(sBg0 + kt, Bg + dst0);
        gload_lds16(sBg1 + kt, Bg + dst1);
        gload_lds16(sBu0 + kt, Bu + dst0);
        gload_lds16(sBu1 + kt, Bu + dst1);
        __syncthreads();
        #pragma unroll
        for (int ks = 0; ks < 2; ks++) {
            bf16x8 a = *(const bf16x8*)&As[offA[ks]];
            #pragma unroll
            for (int j = 0; j < 4; j++) {
                bf16x8 bg = *(const bf16x8*)&Bg[offB[ks][j]];
                bf16x8 bu = *(const bf16x8*)&Bu[offB[ks][j]];
                ag[j] = __builtin_amdgcn_mfma_f32_16x16x32_bf16(a, bg, ag[j], 0, 0, 0);
                au[j] = __builtin_amdgcn_mfma_f32_16x16x32_bf16(a, bu, au[j], 0, 0, 0);
            }
        }
        __syncthreads();
    }
    #pragma unroll
    for (int j = 0; j < 4; j++)
        #pragma unroll
        for (int r = 0; r < 4; r++) {
            int m = m0 + wave * 16 + quad * 4 + r;
            if (m < nt) {
                float g = ag[j][r], u = au[j][r];
                float a = g / (1.f + __expf(-g)) * u;
                act[(size_t)(base + m) * FF_ + n0 + j * 16 + ml] = __float2bfloat16(a);
            }
        }
}

// ---- fallback w1 (f32 weights) — round-7 verified ----
__global__ __launch_bounds__(256) void k_moe_w1(const bf16* __restrict__ h2,
                                                const float* __restrict__ w1,
                                                const int* __restrict__ cnt,
                                                const int* __restrict__ off,
                                                const int* __restrict__ tok_list,
                                                bf16* __restrict__ act) {
    int e = blockIdx.y >> 4, mt = blockIdx.y & 15;
    int m0 = mt * 128;
    int nt = min(cnt[e], T_);
    if (m0 >= nt) return;
    int n0 = blockIdx.x * 64;
    int base = off[e];
    __shared__ bf16 As[128][40];
    __shared__ bf16 Bg[64][40];
    __shared__ bf16 Bu[64][40];
    __shared__ int  toks[128];
    int tid = threadIdx.x;
    if (tid < 128) {
        int m = m0 + tid;
        toks[tid] = ((m < nt) ? tok_list[e * T_ + m] : tok_list[e * T_]) & (T_ - 1);
    }
    __syncthreads();
    const float* w1e = w1 + (size_t)e * 2 * FF_ * D_;
    int wave = tid >> 6, lane = tid & 63, ml = lane & 15, quad = lane >> 4;
    int wm = wave * 32;
    f32x4 ag[2][4] = {}, au[2][4] = {};
    for (int kt = 0; kt < D_; kt += 32) {
        #pragma unroll
        for (int p = 0; p < 2; p++) {
            int ch = p * 256 + tid, row = ch >> 2, c8 = (ch & 3) << 3;
            *(uint4*)&As[row][c8] = *(const uint4*)&h2[(size_t)toks[row] * D_ + kt + c8];
        }
        #pragma unroll
        for (int p = 0; p < 2; p++) {
            int ch = p * 256 + tid, row = ch >> 3, c4 = (ch & 7) << 2;
            float4 vg = *(const float4*)&w1e[(size_t)(n0 + row) * D_ + kt + c4];
            float4 vu = *(const float4*)&w1e[(size_t)(FF_ + n0 + row) * D_ + kt + c4];
            uint2 wg; wg.x = pk2(vg.x, vg.y); wg.y = pk2(vg.z, vg.w);
            uint2 wu; wu.x = pk2(vu.x, vu.y); wu.y = pk2(vu.z, vu.w);
            *(uint2*)&Bg[row][c4] = wg;
            *(uint2*)&Bu[row][c4] = wu;
        }
        __syncthreads();
        bf16x8 a[2], bg[4], bu[4];
        #pragma unroll
        for (int i = 0; i < 2; i++) a[i] = *(const bf16x8*)&As[wm + i * 16 + ml][quad * 8];
        #pragma unroll
        for (int j = 0; j < 4; j++) {
            bg[j] = *(const bf16x8*)&Bg[j * 16 + ml][quad * 8];
            bu[j] = *(const bf16x8*)&Bu[j * 16 + ml][quad * 8];
        }
        #pragma unroll
        for (int i = 0; i < 2; i++)
            #pragma unroll
            for (int j = 0; j < 4; j++) {
                ag[i][j] = __builtin_amdgcn_mfma_f32_16x16x32_bf16(a[i], bg[j], ag[i][j], 0, 0, 0);
                au[i][j] = __builtin_amdgcn_mfma_f32_16x16x32_bf16(a[i], bu[j], au[i][j], 0, 0, 0);
            }
        __syncthreads();
    }
    #pragma unroll
    for (int i = 0; i < 2; i++)
        #pragma unroll
        for (int j = 0; j < 4; j++)
            #pragma unroll
            for (int r = 0; r < 4; r++) {
                int m = m0 + wm + i * 16 + quad * 4 + r;
                if (m < nt) {
                    float g = ag[i][j][r], u = au[i][j][r];
                    float a = g / (1.f + __expf(-g)) * u;
                    act[(size_t)(base + m) * FF_ + n0 + j * 16 + ml] = __float2bfloat16(a);
                }
            }
}

// ======== MoE w2 (MFMA), 64-token tiles, BK=64 K-step (round-11 verified) ========
__global__ __launch_bounds__(256) void k_moe_w2_pre(const bf16* __restrict__ act,
                                                    const bf16* __restrict__ w2b,
                                                    const int* __restrict__ cnt,
                                                    const int* __restrict__ off,
                                                    const int* __restrict__ tok_list,
                                                    const float* __restrict__ tok_w,
                                                    float* __restrict__ out0) {
    int e = blockIdx.y >> 5, mt = blockIdx.y & 31;   // T/64 = 32 m-tiles
    int m0 = mt * 64;
    int nt = min(cnt[e], T_);
    if (m0 >= nt) return;
    int n0 = blockIdx.x * 128;
    int base = off[e];
    __shared__ bf16 As[64 * 64];    // 8 KB
    __shared__ bf16 Bs[128 * 64];   // 16 KB
    int tid = threadIdx.x;
    int wave = tid >> 6, lane = tid & 63, ml = lane & 15, quad = lane >> 4;
    int wm = (wave >> 1) * 32, wn = (wave & 1) * 64;
    const bf16* w2e = w2b + (size_t)e * D_ * FF_;
    // A: 512 chunks (2/thread); B: 1024 chunks (4/thread). Rows beyond nt read
    // adjacent valid workspace; their acc rows are masked at store.
    int r0 = tid >> 3, q0 = tid & 7;
    int ra1 = 32 + r0;
    int ca0 = (q0 ^ (r0 & 7)) << 3;
    int ca1 = (q0 ^ (ra1 & 7)) << 3;
    const bf16* sA0 = act + (size_t)(base + m0 + r0)  * FF_ + ca0;
    const bf16* sA1 = act + (size_t)(base + m0 + ra1) * FF_ + ca1;
    const bf16* sB[4];
    #pragma unroll
    for (int g = 0; g < 4; g++) {
        int rb = g * 32 + r0;
        int cb = (q0 ^ (rb & 7)) << 3;
        sB[g] = w2e + (size_t)(n0 + rb) * FF_ + cb;
    }
    int dstA0 = wave * 512, dstA1 = 2048 + wave * 512;
    int offA[2][2], offB[2][4];
    #pragma unroll
    for (int ks = 0; ks < 2; ks++) {
        int cq = ks * 4 + quad;
        #pragma unroll
        for (int i = 0; i < 2; i++) {
            int ra = wm + i * 16 + ml;
            offA[ks][i] = ra * 64 + ((cq ^ (ra & 7)) << 3);
        }
        #pragma unroll
        for (int j = 0; j < 4; j++) {
            int rb = wn + j * 16 + ml;
            offB[ks][j] = rb * 64 + ((cq ^ (rb & 7)) << 3);
        }
    }
    f32x4 acc[2][4] = {};
    for (int kt = 0; kt < FF_; kt += 64) {
        gload_lds16(sA0 + kt, As + dstA0);
        gload_lds16(sA1 + kt, As + dstA1);
        #pragma unroll
        for (int g = 0; g < 4; g++)
            gload_lds16(sB[g] + kt, Bs + g * 2048 + wave * 512);
        __syncthreads();
        #pragma unroll
        for (int ks = 0; ks < 2; ks++) {
            bf16x8 a[2], b[4];
            #pragma unroll
            for (int i = 0; i < 2; i++) a[i] = *(const bf16x8*)&As[offA[ks][i]];
            #pragma unroll
            for (int j = 0; j < 4; j++) b[j] = *(const bf16x8*)&Bs[offB[ks][j]];
            #pragma unroll
            for (int i = 0; i < 2; i++)
                #pragma unroll
                for (int j = 0; j < 4; j++)
                    acc[i][j] = __builtin_amdgcn_mfma_f32_16x16x32_bf16(a[i], b[j], acc[i][j], 0, 0, 0);
        }
        __syncthreads();
    }
    #pragma unroll
    for (int i = 0; i < 2; i++)
        #pragma unroll
        for (int r = 0; r < 4; r++) {
            int m = m0 + wm + i * 16 + quad * 4 + r;
            if (m < nt) {
                int   tok = tok_list[e * T_ + m] & (T_ - 1);
                float wgt = tok_w[e * T_ + m];
                #pragma unroll
                for (int j = 0; j < 4; j++) {
                    int col = n0 + wn + j * 16 + ml;
                    atomicAdd(&out0[(size_t)tok * D_ + col], wgt * acc[i][j][r]);
                }
            }
        }
}

// ---- fallback w2 (f32 weights) — round-7 verified ----
__global__ __launch_bounds__(256) void k_moe_w2(const bf16* __restrict__ act,
                                                const float* __restrict__ w2,
                                                const int* __restrict__ cnt,
                                                const int* __restrict__ off,
                                                const int* __restrict__ tok_list,
                                                const float* __restrict__ tok_w,
                                                float* __restrict__ out0) {
    int e = blockIdx.y >> 4, mt = blockIdx.y & 15;
    int m0 = mt * 128;
    int nt = min(cnt[e], T_);
    if (m0 >= nt) return;
    int n0 = blockIdx.x * 128;
    int base = off[e];
    __shared__ bf16 As[128][40];
    __shared__ bf16 Bs[128][40];
    int tid = threadIdx.x;
    int wave = tid >> 6, lane = tid & 63, ml = lane & 15, quad = lane >> 4;
    int wm = (wave >> 1) * 64, wn = (wave & 1) * 64;
    const float* w2e = w2 + (size_t)e * D_ * FF_;
    f32x4 acc[4][4] = {};
    for (int kt = 0; kt < FF_; kt += 32) {
        #pragma unroll
        for (int p = 0; p < 2; p++) {
            int ch = p * 256 + tid, row = ch >> 2, c8 = (ch & 3) << 3;
            uint4 v = make_uint4(0, 0, 0, 0);
            if (m0 + row < nt) v = *(const uint4*)&act[(size_t)(base + m0 + row) * FF_ + kt + c8];
            *(uint4*)&As[row][c8] = v;
        }
        #pragma unroll
        for (int p = 0; p < 4; p++) {
            int ch = p * 256 + tid, row = ch >> 3, c4 = (ch & 7) << 2;
            float4 v = *(const float4*)&w2e[(size_t)(n0 + row) * FF_ + kt + c4];
            uint2 w; w.x = pk2(v.x, v.y); w.y = pk2(v.z, v.w);
            *(uint2*)&Bs[row][c4] = w;
        }
        __syncthreads();
        bf16x8 a[4], b[4];
        #pragma unroll
        for (int i = 0; i < 4; i++) a[i] = *(const bf16x8*)&As[wm + i * 16 + ml][quad * 8];
        #pragma unroll
        for (int j = 0; j < 4; j++) b[j] = *(const bf16x8*)&Bs[wn + j * 16 + ml][quad * 8];
        #pragma unroll
        for (int i = 0; i < 4; i++)
            #pragma unroll
            for (int j = 0; j < 4; j++)
                acc[i][j] = __builtin_amdgcn_mfma_f32_16x16x32_bf16(a[i], b[j], acc[i][j], 0, 0, 0);
        __syncthreads();
    }
    #pragma unroll
    for (int i = 0; i < 4; i++)
        #pragma unroll
        for (int r = 0; r < 4; r++) {
            int m = m0 + wm + i * 16 + quad * 4 + r;
            if (m < nt) {
                int   tok = tok_list[e * T_ + m] & (T_ - 1);
                float wgt = tok_w[e * T_ + m];
                #pragma unroll
                for (int j = 0; j < 4; j++) {
                    int col = n0 + wn + j * 16 + ml;
                    atomicAdd(&out0[(size_t)tok * D_ + col], wgt * acc[i][j][r]);
                }
            }
        }
}

extern "C" void kernel_launch(void* const* d_in, const int* in_sizes, int n_in,
                              void* d_out, int out_size, void* d_ws, size_t ws_size,
                              hipStream_t stream) {
    const float* hidden     = (const float*)d_in[0];
    const float* residual   = (const float*)d_in[1];
    const float* op_norm_w  = (const float*)d_in[2];
    const float* ffn_norm_w = (const float*)d_in[3];
    const float* in_proj_w  = (const float*)d_in[4];
    const float* conv_w     = (const float*)d_in[5];
    const float* out_proj_w = (const float*)d_in[6];
    const float* gate_w     = (const float*)d_in[7];
    const float* gate_bias  = (const float*)d_in[8];
    const float* w1         = (const float*)d_in[9];
    const float* w2         = (const float*)d_in[10];

    // ---- base workspace (~32.5 MB) ----
    char* p = (char*)d_ws;
    int*    cnt        = (int*)p;        p += 256;   // cnt[0..15]; cnt[31] = done flag
    int*    off        = (int*)p;        p += 128;
    int*    tok_list   = (int*)p;        p += (size_t)E_ * T_ * 4;      // 128 KB
    float*  tok_w      = (float*)p;      p += (size_t)E_ * T_ * 4;      // 128 KB
    int4*   choice_idx = (int4*)p;       p += (size_t)T_ * 16;          // 32 KB
    float4* choice_wgt = (float4*)p;     p += (size_t)T_ * 16;          // 32 KB
    char*   regA       = p;              p += (size_t)T_ * D_ * 2 * 2;  // 8 MB
    char*   regB       = p;              p += (size_t)T_ * 3 * D_ * 4;  // 24 MB

    // pre-converted weight area (~64 MB, optional)
    const size_t n1 = (size_t)E_ * 2 * FF_ * D_;   // w1 elements
    const size_t n2 = (size_t)E_ * D_ * FF_;       // w2
    const size_t n3 = (size_t)3 * D_ * D_;         // in_proj
    const size_t n4 = (size_t)D_ * D_;             // out_proj
    bf16* w1b = (bf16*)p;  p += n1 * 2;
    bf16* w2b = (bf16*)p;  p += n2 * 2;
    bf16* iph = (bf16*)p;  p += n3 * 2;
    bf16* ipl = (bf16*)p;  p += n3 * 2;
    bf16* oph = (bf16*)p;  p += n4 * 2;
    bf16* opl = (bf16*)p;  p += n4 * 2;
    bool pre = ((size_t)(p - (char*)d_ws) <= ws_size);

    // regA: h1hi/h1lo -> cchi/cclo -> act (compact 8192 x FF bf16)
    bf16* h1hi = (bf16*)regA;
    bf16* h1lo = (bf16*)(regA + (size_t)T_ * D_ * 2);
    bf16* cchi = h1hi;
    bf16* cclo = h1lo;
    bf16* act  = (bf16*)regA;
    // regB: bcx (f32, 24 MB) -> y f32 [0:8) + h2b bf16 [16:20)
    float* bcx = (float*)regB;
    float* y   = (float*)regB;
    bf16*  h2b = (bf16*)(regB + (size_t)T_ * D_ * 8);

    float* out0 = (float*)d_out;                    // MoE output [T,D], f32 atomically accumulated
    float* res  = out0 + (size_t)T_ * D_;           // residual slot

    if (pre) {
        int nq = (int)((n1 + n2 + n3 + n4) / 8 / 256);   // 14336 blocks (8 elems/thread)
        k_convert<<<nq, 256, 0, stream>>>(w1, w2, in_proj_w, out_proj_w,
                                          w1b, w2b, iph, ipl, oph, opl);
    }
    k_addnorm1z<<<T_, 256, 0, stream>>>(hidden, residual, op_norm_w, h1hi, h1lo, res, out0);
    if (pre)
        k_gemm_small<128><<<dim3(3 * D_ / 128, T_ / 64), 256, 0, stream>>>(
            h1hi, h1lo, iph, ipl, bcx, T_, 3 * D_, D_);
    else
        k_gemm_split<<<dim3(3 * D_ / 128, T_ / 128), 256, 0, stream>>>(
            h1hi, h1lo, in_proj_w, bcx, T_, 3 * D_, D_);
    k_conv2<<<T_, 256, 0, stream>>>(bcx, conv_w, cchi, cclo, cnt);
    if (pre)
        k_gemm_small<64><<<dim3(D_ / 64, T_ / 64), 256, 0, stream>>>(
            cchi, cclo, oph, opl, y, T_, D_, D_);
    else
        k_gemm_split<<<dim3(D_ / 128, T_ / 128), 256, 0, stream>>>(
            cchi, cclo, out_proj_w, y, T_, D_, D_);
    k_an2_gate<<<T_, 256, 0, stream>>>(y, res, ffn_norm_w, h2b, gate_w, gate_bias,
                                       choice_idx, choice_wgt);
    k_scatter2<<<E_, 256, 0, stream>>>(choice_idx, choice_wgt, cnt, tok_list, tok_w,
                                       off, &cnt[31]);
    if (pre) {
        k_moe_w1_pre<<<dim3(FF_ / 64, E_ * (T_ / 64)), 256, 0, stream>>>(
            h2b, w1b, cnt, off, tok_list, act);
        k_moe_w2_pre<<<dim3(D_ / 128, E_ * (T_ / 64)), 256, 0, stream>>>(
            act, w2b, cnt, off, tok_list, tok_w, out0);
    } else {
        k_moe_w1<<<dim3(FF_ / 64, E_ * (T_ / 128)), 256, 0, stream>>>(
            h2b, w1, cnt, off, tok_list, act);
        k_moe_w2<<<dim3(D_ / 128, E_ * (T_ / 128)), 256, 0, stream>>>(
            act, w2, cnt, off, tok_list, tok_w, out0);
    }
}

// Round 14
// 355.483 us; speedup vs baseline: 1.0173x; 1.0173x over previous
//
#include <hip/hip_runtime.h>
#include <hip/hip_bf16.h>

// Problem constants (fixed by the reference)
#define T_  2048
#define D_  1024
#define FF_ 512
#define E_  16
#define K_  4
#define L_  3
static constexpr float EPS = 1e-5f;

typedef __hip_bfloat16 bf16;
typedef __attribute__((ext_vector_type(8))) short bf16x8;   // MFMA A/B frag (4 VGPRs)
typedef __attribute__((ext_vector_type(4))) float f32x4;    // MFMA C/D frag

__device__ __forceinline__ float b2f(bf16 x) { return __bfloat162float(x); }

__device__ __forceinline__ unsigned int pk2(float a, float b) {
    __hip_bfloat162 h = __float22bfloat162_rn(make_float2(a, b));
    unsigned int u; __builtin_memcpy(&u, &h, 4); return u;
}

// async global->LDS, 16B per lane. Dest must be wave-uniform base; HW writes base + lane*16.
__device__ __forceinline__ void gload_lds16(const bf16* g, bf16* l) {
    __builtin_amdgcn_global_load_lds(
        (const __attribute__((address_space(1))) unsigned int*)g,
        (__attribute__((address_space(3))) unsigned int*)l, 16, 0, 0);
}

// split f32x4 into bf16 hi + bf16 lo packed pairs (hi+lo ~ f32 precision)
__device__ __forceinline__ void split_pack(float4 v, uint2 &hi, uint2 &lo) {
    __hip_bfloat162 h01 = __float22bfloat162_rn(make_float2(v.x, v.y));
    __hip_bfloat162 h23 = __float22bfloat162_rn(make_float2(v.z, v.w));
    float2 r01 = make_float2(v.x - __bfloat162float(h01.x), v.y - __bfloat162float(h01.y));
    float2 r23 = make_float2(v.z - __bfloat162float(h23.x), v.w - __bfloat162float(h23.y));
    __hip_bfloat162 l01 = __float22bfloat162_rn(r01);
    __hip_bfloat162 l23 = __float22bfloat162_rn(r23);
    __builtin_memcpy(&hi.x, &h01, 4); __builtin_memcpy(&hi.y, &h23, 4);
    __builtin_memcpy(&lo.x, &l01, 4); __builtin_memcpy(&lo.y, &l23, 4);
}

// ================= weight pre-conversion (round-13 verified, 8 f32/thread) =================
__global__ __launch_bounds__(256) void k_convert(const float* __restrict__ w1,
                                                 const float* __restrict__ w2,
                                                 const float* __restrict__ ipw,
                                                 const float* __restrict__ opw,
                                                 bf16* __restrict__ w1b,
                                                 bf16* __restrict__ w2b,
                                                 bf16* __restrict__ iph,
                                                 bf16* __restrict__ ipl,
                                                 bf16* __restrict__ oph,
                                                 bf16* __restrict__ opl) {
    const size_t n1 = (size_t)E_ * 2 * FF_ * D_;   // 16M
    const size_t n2 = (size_t)E_ * D_ * FF_;       // 8M
    const size_t n3 = (size_t)3 * D_ * D_;         // 3M
    const size_t n4 = (size_t)D_ * D_;             // 1M
    size_t i = ((size_t)blockIdx.x * 256 + threadIdx.x) * 8;
    if (i < n1) {
        float4 a = *(const float4*)&w1[i];
        float4 b = *(const float4*)&w1[i + 4];
        uint4 h; h.x = pk2(a.x, a.y); h.y = pk2(a.z, a.w);
        h.z = pk2(b.x, b.y); h.w = pk2(b.z, b.w);
        *(uint4*)&w1b[i] = h;
    } else if (i < n1 + n2) {
        size_t j = i - n1;
        float4 a = *(const float4*)&w2[j];
        float4 b = *(const float4*)&w2[j + 4];
        uint4 h; h.x = pk2(a.x, a.y); h.y = pk2(a.z, a.w);
        h.z = pk2(b.x, b.y); h.w = pk2(b.z, b.w);
        *(uint4*)&w2b[j] = h;
    } else if (i < n1 + n2 + n3) {
        size_t j = i - n1 - n2;
        float4 a = *(const float4*)&ipw[j];
        float4 b = *(const float4*)&ipw[j + 4];
        uint2 h0, l0, h1, l1;
        split_pack(a, h0, l0); split_pack(b, h1, l1);
        uint4 hh = make_uint4(h0.x, h0.y, h1.x, h1.y);
        uint4 ll = make_uint4(l0.x, l0.y, l1.x, l1.y);
        *(uint4*)&iph[j] = hh;
        *(uint4*)&ipl[j] = ll;
    } else if (i < n1 + n2 + n3 + n4) {
        size_t j = i - n1 - n2 - n3;
        float4 a = *(const float4*)&opw[j];
        float4 b = *(const float4*)&opw[j + 4];
        uint2 h0, l0, h1, l1;
        split_pack(a, h0, l0); split_pack(b, h1, l1);
        uint4 hh = make_uint4(h0.x, h0.y, h1.x, h1.y);
        uint4 ll = make_uint4(l0.x, l0.y, l1.x, l1.y);
        *(uint4*)&oph[j] = hh;
        *(uint4*)&opl[j] = ll;
    }
}

// ---------------- block reduction ----------------
__device__ __forceinline__ float blockReduceSum(float v) {
    #pragma unroll
    for (int off = 32; off > 0; off >>= 1) v += __shfl_down(v, off, 64);
    __shared__ float s[4];
    __shared__ float tot;
    int lane = threadIdx.x & 63, wid = threadIdx.x >> 6;
    if (lane == 0) s[wid] = v;
    __syncthreads();
    if (threadIdx.x == 0) tot = s[0] + s[1] + s[2] + s[3];
    __syncthreads();
    return tot;
}

// ---------------- addnorm1 + zero out0 (fused; zero needed only by fallback path) --------
__global__ __launch_bounds__(256) void k_addnorm1z(const float* __restrict__ x,
                                                   const float* __restrict__ r,
                                                   const float* __restrict__ w,
                                                   bf16* __restrict__ hhi,
                                                   bf16* __restrict__ hlo,
                                                   float* __restrict__ res,
                                                   float* __restrict__ out0) {
    int t = blockIdx.x, tid = threadIdx.x;
    float v[4]; float ss = 0.f;
    #pragma unroll
    for (int i = 0; i < 4; i++) {
        int d = tid + 256 * i;
        float s = x[(size_t)t * D_ + d] + r[(size_t)t * D_ + d];
        v[i] = s; ss += s * s;
        out0[(size_t)t * D_ + d] = 0.f;
    }
    float tot = blockReduceSum(ss);
    float rs = rsqrtf(tot / (float)D_ + EPS);
    #pragma unroll
    for (int i = 0; i < 4; i++) {
        int d = tid + 256 * i;
        res[(size_t)t * D_ + d] = v[i];
        float val = v[i] * rs * w[d];
        bf16 hi = __float2bfloat16(val);
        hhi[(size_t)t * D_ + d] = hi;
        hlo[(size_t)t * D_ + d] = __float2bfloat16(val - b2f(hi));
    }
}

// ======== split-precision MFMA GEMM, 64xTN tiles, BK=64 K-step (round-12 verified) ========
template<int TN>
__global__ __launch_bounds__(256) void k_gemm_small(const bf16* __restrict__ Ah,
                                                    const bf16* __restrict__ Al,
                                                    const bf16* __restrict__ Bh,
                                                    const bf16* __restrict__ Bl,
                                                    float* __restrict__ C,
                                                    int M, int N, int K) {
    constexpr int NF  = TN / 64;         // B frags per wave (16-wide each)
    constexpr int NBG = TN / 32;         // B staging row-groups (32 rows each)
    __shared__ bf16 Ash[64 * 64];
    __shared__ bf16 Asl[64 * 64];
    __shared__ bf16 Bsh[TN * 64];
    __shared__ bf16 Bsl[TN * 64];
    int m0 = blockIdx.y * 64, n0 = blockIdx.x * TN;
    int tid = threadIdx.x;
    int wave = tid >> 6, lane = tid & 63, ml = lane & 15, quad = lane >> 4;
    int wn = wave * (TN / 4);
    // staging: thread handles chunk g*256+tid (row g*32 + tid>>3, phys chunk tid&7)
    int r0 = tid >> 3, q0 = tid & 7;
    const bf16 *sAh[2], *sAl[2];
    #pragma unroll
    for (int g = 0; g < 2; g++) {
        int ra = g * 32 + r0;
        int c = (q0 ^ (ra & 7)) << 3;                 // pre-swizzled source column
        sAh[g] = Ah + (size_t)(m0 + ra) * K + c;
        sAl[g] = Al + (size_t)(m0 + ra) * K + c;
    }
    const bf16 *sBh[NBG], *sBl[NBG];
    #pragma unroll
    for (int g = 0; g < NBG; g++) {
        int rb = g * 32 + r0;
        int c = (q0 ^ (rb & 7)) << 3;
        sBh[g] = Bh + (size_t)(n0 + rb) * K + c;
        sBl[g] = Bl + (size_t)(n0 + rb) * K + c;
    }
    int offA[2][4], offB[2][NF];
    #pragma unroll
    for (int ks = 0; ks < 2; ks++) {
        int cq = ks * 4 + quad;                       // logical chunk for this k-subtile
        #pragma unroll
        for (int i = 0; i < 4; i++) {
            int ra = i * 16 + ml;
            offA[ks][i] = ra * 64 + ((cq ^ (ra & 7)) << 3);
        }
        #pragma unroll
        for (int j = 0; j < NF; j++) {
            int rb = wn + j * 16 + ml;
            offB[ks][j] = rb * 64 + ((cq ^ (rb & 7)) << 3);
        }
    }
    f32x4 acc[4][NF] = {};
    for (int kt = 0; kt < K; kt += 64) {
        #pragma unroll
        for (int g = 0; g < 2; g++) {
            gload_lds16(sAh[g] + kt, Ash + g * 2048 + wave * 512);
            gload_lds16(sAl[g] + kt, Asl + g * 2048 + wave * 512);
        }
        #pragma unroll
        for (int g = 0; g < NBG; g++) {
            gload_lds16(sBh[g] + kt, Bsh + g * 2048 + wave * 512);
            gload_lds16(sBl[g] + kt, Bsl + g * 2048 + wave * 512);
        }
        __syncthreads();
        #pragma unroll
        for (int ks = 0; ks < 2; ks++) {
            bf16x8 ah[4], al[4], bh[NF], bl[NF];
            #pragma unroll
            for (int i = 0; i < 4; i++) {
                ah[i] = *(const bf16x8*)&Ash[offA[ks][i]];
                al[i] = *(const bf16x8*)&Asl[offA[ks][i]];
            }
            #pragma unroll
            for (int j = 0; j < NF; j++) {
                bh[j] = *(const bf16x8*)&Bsh[offB[ks][j]];
                bl[j] = *(const bf16x8*)&Bsl[offB[ks][j]];
            }
            #pragma unroll
            for (int i = 0; i < 4; i++)
                #pragma unroll
                for (int j = 0; j < NF; j++) {
                    acc[i][j] = __builtin_amdgcn_mfma_f32_16x16x32_bf16(ah[i], bh[j], acc[i][j], 0, 0, 0);
                    acc[i][j] = __builtin_amdgcn_mfma_f32_16x16x32_bf16(al[i], bh[j], acc[i][j], 0, 0, 0);
                    acc[i][j] = __builtin_amdgcn_mfma_f32_16x16x32_bf16(ah[i], bl[j], acc[i][j], 0, 0, 0);
                }
        }
        __syncthreads();
    }
    #pragma unroll
    for (int i = 0; i < 4; i++)
        #pragma unroll
        for (int j = 0; j < NF; j++)
            #pragma unroll
            for (int r = 0; r < 4; r++) {
                int row = m0 + i * 16 + quad * 4 + r;        // C/D: row = quad*4+reg
                int col = n0 + wn + j * 16 + ml;             //      col = lane&15
                C[(size_t)row * N + col] = acc[i][j][r];
            }
}

// ---- fallback (f32 B, in-block split) — round-7 verified ----
__global__ __launch_bounds__(256) void k_gemm_split(const bf16* __restrict__ Ah,
                                                    const bf16* __restrict__ Al,
                                                    const float* __restrict__ B,
                                                    float* __restrict__ C,
                                                    int M, int N, int K) {
    __shared__ bf16 Ash[128][40];
    __shared__ bf16 Asl[128][40];
    __shared__ bf16 Bsh[128][40];
    __shared__ bf16 Bsl[128][40];
    int m0 = blockIdx.y * 128, n0 = blockIdx.x * 128;
    int tid = threadIdx.x;
    int wave = tid >> 6, lane = tid & 63, ml = lane & 15, quad = lane >> 4;
    int wm = (wave >> 1) * 64, wn = (wave & 1) * 64;
    f32x4 acc[4][4] = {};
    for (int kt = 0; kt < K; kt += 32) {
        #pragma unroll
        for (int p = 0; p < 2; p++) {
            int ch = p * 256 + tid, row = ch >> 2, c8 = (ch & 3) << 3;
            *(uint4*)&Ash[row][c8] = *(const uint4*)&Ah[(size_t)(m0 + row) * K + kt + c8];
            *(uint4*)&Asl[row][c8] = *(const uint4*)&Al[(size_t)(m0 + row) * K + kt + c8];
        }
        #pragma unroll
        for (int p = 0; p < 4; p++) {
            int ch = p * 256 + tid, row = ch >> 3, c4 = (ch & 7) << 2;
            float4 v = *(const float4*)&B[(size_t)(n0 + row) * K + kt + c4];
            uint2 hi, lo; split_pack(v, hi, lo);
            *(uint2*)&Bsh[row][c4] = hi;
            *(uint2*)&Bsl[row][c4] = lo;
        }
        __syncthreads();
        bf16x8 ah[4], al[4], bh[4], bl[4];
        #pragma unroll
        for (int i = 0; i < 4; i++) {
            ah[i] = *(const bf16x8*)&Ash[wm + i * 16 + ml][quad * 8];
            al[i] = *(const bf16x8*)&Asl[wm + i * 16 + ml][quad * 8];
        }
        #pragma unroll
        for (int j = 0; j < 4; j++) {
            bh[j] = *(const bf16x8*)&Bsh[wn + j * 16 + ml][quad * 8];
            bl[j] = *(const bf16x8*)&Bsl[wn + j * 16 + ml][quad * 8];
        }
        #pragma unroll
        for (int i = 0; i < 4; i++)
            #pragma unroll
            for (int j = 0; j < 4; j++) {
                acc[i][j] = __builtin_amdgcn_mfma_f32_16x16x32_bf16(ah[i], bh[j], acc[i][j], 0, 0, 0);
                acc[i][j] = __builtin_amdgcn_mfma_f32_16x16x32_bf16(al[i], bh[j], acc[i][j], 0, 0, 0);
                acc[i][j] = __builtin_amdgcn_mfma_f32_16x16x32_bf16(ah[i], bl[j], acc[i][j], 0, 0, 0);
            }
        __syncthreads();
    }
    #pragma unroll
    for (int i = 0; i < 4; i++)
        #pragma unroll
        for (int j = 0; j < 4; j++)
            #pragma unroll
            for (int r = 0; r < 4; r++) {
                int row = m0 + wm + i * 16 + quad * 4 + r;
                int col = n0 + wn + j * 16 + ml;
                C[(size_t)row * N + col] = acc[i][j][r];
            }
}

// ---------------- conv (+ zero cnt/done control block, fused) ----------------
__global__ __launch_bounds__(256) void k_conv2(const float* __restrict__ bcx,
                                               const float* __restrict__ cw,
                                               bf16* __restrict__ cchi,
                                               bf16* __restrict__ cclo,
                                               int* __restrict__ zctl) {
    int t = blockIdx.x, tid = threadIdx.x;
    if (blockIdx.x == 0 && tid < 32) zctl[tid] = 0;   // cnt[0..15] + done slot
    #pragma unroll
    for (int i = 0; i < 4; i++) {
        int d = tid + 256 * i;
        float acc = 0.f;
        #pragma unroll
        for (int l = 0; l < L_; l++) {
            int tt = t + l - (L_ - 1);
            if (tt >= 0) {
                float bb = bcx[(size_t)tt * 3 * D_ + d];
                float xx = bcx[(size_t)tt * 3 * D_ + 2 * D_ + d];
                acc += bb * xx * cw[d * L_ + l];
            }
        }
        float c = bcx[(size_t)t * 3 * D_ + D_ + d];
        float val = c * acc;
        bf16 hi = __float2bfloat16(val);
        cchi[(size_t)t * D_ + d] = hi;
        cclo[(size_t)t * D_ + d] = __float2bfloat16(val - b2f(hi));
    }
}

// ---------------- addnorm2 + gate (fused; h2 f32 never materialized) ----------------
__global__ __launch_bounds__(256) void k_an2_gate(const float* __restrict__ y,
                                                  float* __restrict__ res,
                                                  const float* __restrict__ w,
                                                  bf16* __restrict__ h2b,
                                                  const float* __restrict__ gw,
                                                  const float* __restrict__ gb,
                                                  int4* __restrict__ choice_idx,
                                                  float4* __restrict__ choice_wgt) {
    int t = blockIdx.x, tid = threadIdx.x;
    __shared__ float hs[D_];
    __shared__ float logits[E_];
    float v[4]; float ss = 0.f;
    #pragma unroll
    for (int i = 0; i < 4; i++) {
        int d = tid + 256 * i;
        float s = y[(size_t)t * D_ + d] + res[(size_t)t * D_ + d];
        v[i] = s; ss += s * s;
    }
    float tot = blockReduceSum(ss);
    float rs = rsqrtf(tot / (float)D_ + EPS);
    #pragma unroll
    for (int i = 0; i < 4; i++) {
        int d = tid + 256 * i;
        res[(size_t)t * D_ + d] = v[i];
        float val = v[i] * rs * w[d];
        h2b[(size_t)t * D_ + d] = __float2bfloat16(val);
        hs[d] = val;
    }
    __syncthreads();
    int e = tid >> 4, j = tid & 15;
    float p = 0.f;
    for (int d = j; d < D_; d += 16) p += hs[d] * gw[(size_t)e * D_ + d];
    #pragma unroll
    for (int off = 8; off > 0; off >>= 1) p += __shfl_down(p, off, 64);
    if (j == 0) logits[e] = p;
    __syncthreads();
    if (tid == 0) {
        float sc[E_], ch[E_];
        #pragma unroll
        for (int i = 0; i < E_; i++) {
            float s = 1.f / (1.f + expf(-logits[i]));
            sc[i] = s; ch[i] = s + gb[i];
        }
        int idx[K_]; float wv[K_]; float wsum = 0.f;
        bool used[E_] = {};
        #pragma unroll
        for (int k = 0; k < K_; k++) {
            int best = 0; float bv = -1e30f;
            for (int i = 0; i < E_; i++)
                if (!used[i] && ch[i] > bv) { bv = ch[i]; best = i; }
            used[best] = true; idx[k] = best; wv[k] = sc[best]; wsum += sc[best];
        }
        float inv = 1.f / (wsum + 1e-20f);
        choice_idx[t] = make_int4(idx[0], idx[1], idx[2], idx[3]);
        choice_wgt[t] = make_float4(wv[0] * inv, wv[1] * inv, wv[2] * inv, wv[3] * inv);
    }
}

// ---------------- scatter + last-block scan (fused) + per-(t,k) position record ---------
__global__ __launch_bounds__(256) void k_scatter2(const int4* __restrict__ choice_idx,
                                                  const float4* __restrict__ choice_wgt,
                                                  int* __restrict__ cnt,
                                                  int* __restrict__ tok_list,
                                                  float* __restrict__ tok_w,
                                                  int* __restrict__ pos4,
                                                  int* __restrict__ off,
                                                  int* __restrict__ done) {
    int e = blockIdx.x;
    __shared__ int ctr;
    if (threadIdx.x == 0) ctr = 0;
    __syncthreads();
    int lane = threadIdx.x & 63;
    for (int t = threadIdx.x; t < T_; t += 256) {
        int4   ci = choice_idx[t];
        float4 cw = choice_wgt[t];
        int kidx = -1; float w = 0.f;
        if (ci.x == e)      { kidx = 0; w = cw.x; }
        else if (ci.y == e) { kidx = 1; w = cw.y; }
        else if (ci.z == e) { kidx = 2; w = cw.z; }
        else if (ci.w == e) { kidx = 3; w = cw.w; }
        bool m = (kidx >= 0);
        unsigned long long mask = __ballot(m);
        int loff = __popcll(mask & ((1ull << lane) - 1ull));
        int wcnt = __popcll(mask);
        int base = 0;
        if (lane == 0 && wcnt > 0) base = atomicAdd(&ctr, wcnt);
        base = __shfl(base, 0, 64);
        if (m) {
            tok_list[e * T_ + base + loff] = t;
            tok_w[e * T_ + base + loff]    = w;
            pos4[t * 4 + kidx]             = base + loff;   // position within e's list
        }
    }
    __syncthreads();
    if (threadIdx.x == 0) {
        atomicExch(&cnt[e], ctr);          // device-scope publish
        __threadfence();
        int prev = atomicAdd(done, 1);
        if (prev == E_ - 1) {              // last block does the scan
            int s = 0;
            for (int i = 0; i < E_; i++) {
                int c = atomicAdd(&cnt[i], 0);   // device-scope read
                off[i] = s; s += min(c, T_);
            }
            off[E_] = s;
        }
    }
}

// ======== MoE w1 (MFMA), 64-token tiles, BK=64 K-step (round-11 verified) ========
__global__ __launch_bounds__(256) void k_moe_w1_pre(const bf16* __restrict__ h2,
                                                    const bf16* __restrict__ w1b,
                                                    const int* __restrict__ cnt,
                                                    const int* __restrict__ off,
                                                    const int* __restrict__ tok_list,
                                                    bf16* __restrict__ act) {
    int e = blockIdx.y >> 5, mt = blockIdx.y & 31;   // T/64 = 32 m-tiles
    int m0 = mt * 64;
    int nt = min(cnt[e], T_);
    if (m0 >= nt) return;
    int n0 = blockIdx.x * 64;
    int base = off[e];
    __shared__ bf16 As[64 * 64];
    __shared__ bf16 Bg[64 * 64];
    __shared__ bf16 Bu[64 * 64];
    int tid = threadIdx.x;
    int wave = tid >> 6, lane = tid & 63, ml = lane & 15, quad = lane >> 4;
    const bf16* w1e = w1b + (size_t)e * 2 * FF_ * D_;
    int r0 = tid >> 3, q0 = tid & 7;
    int r1 = 32 + r0;
    int c0 = (q0 ^ (r0 & 7)) << 3;
    int c1 = (q0 ^ (r1 & 7)) << 3;
    int ma0 = m0 + r0, ma1 = m0 + r1;
    int tok0 = tok_list[e * T_ + (ma0 < nt ? ma0 : 0)] & (T_ - 1);
    int tok1 = tok_list[e * T_ + (ma1 < nt ? ma1 : 0)] & (T_ - 1);
    const bf16* sA0  = h2 + (size_t)tok0 * D_ + c0;
    const bf16* sA1  = h2 + (size_t)tok1 * D_ + c1;
    const bf16* sBg0 = w1e + (size_t)(n0 + r0) * D_ + c0;
    const bf16* sBg1 = w1e + (size_t)(n0 + r1) * D_ + c1;
    const bf16* sBu0 = w1e + (size_t)(FF_ + n0 + r0) * D_ + c0;
    const bf16* sBu1 = w1e + (size_t)(FF_ + n0 + r1) * D_ + c1;
    int dst0 = wave * 512, dst1 = 2048 + wave * 512;   // elem offsets
    int offA[2], offB[2][4];
    #pragma unroll
    for (int ks = 0; ks < 2; ks++) {
        int ra = wave * 16 + ml;
        int cqa = ks * 4 + quad;
        offA[ks] = ra * 64 + ((cqa ^ (ra & 7)) << 3);
        #pragma unroll
        for (int j = 0; j < 4; j++) {
            int rb = j * 16 + ml;
            offB[ks][j] = rb * 64 + ((cqa ^ (rb & 7)) << 3);
        }
    }
    f32x4 ag[4] = {}, au[4] = {};
    for (int kt = 0; kt < D_; kt += 64) {
        gload_lds16(sA0 + kt,  As + dst0);
        gload_lds16(sA1 + kt,  As + dst1);
        gload_lds16(sBg0 + kt, Bg + dst0);
        gload_lds16(sBg1 + kt, Bg + dst1);
        gload_lds16(sBu0 + kt, Bu + dst0);
        gload_lds16(sBu1 + kt, Bu + dst1);
        __syncthreads();
        #pragma unroll
        for (int ks = 0; ks < 2; ks++) {
            bf16x8 a = *(const bf16x8*)&As[offA[ks]];
            #pragma unroll
            for (int j = 0; j < 4; j++) {
                bf16x8 bg = *(const bf16x8*)&Bg[offB[ks][j]];
                bf16x8 bu = *(const bf16x8*)&Bu[offB[ks][j]];
                ag[j] = __builtin_amdgcn_mfma_f32_16x16x32_bf16(a, bg, ag[j], 0, 0, 0);
                au[j] = __builtin_amdgcn_mfma_f32_16x16x32_bf16(a, bu, au[j], 0, 0, 0);
            }
        }
        __syncthreads();
    }
    #pragma unroll
    for (int j = 0; j < 4; j++)
        #pragma unroll
        for (int r = 0; r < 4; r++) {
            int m = m0 + wave * 16 + quad * 4 + r;
            if (m < nt) {
                float g = ag[j][r], u = au[j][r];
                float a = g / (1.f + __expf(-g)) * u;
                act[(size_t)(base + m) * FF_ + n0 + j * 16 + ml] = __float2bfloat16(a);
            }
        }
}

// ---- fallback w1 (f32 weights) — round-7 verified ----
__global__ __launch_bounds__(256) void k_moe_w1(const bf16* __restrict__ h2,
                                                const float* __restrict__ w1,
                                                const int* __restrict__ cnt,
                                                const int* __restrict__ off,
                                                const int* __restrict__ tok_list,
                                                bf16* __restrict__ act) {
    int e = blockIdx.y >> 4, mt = blockIdx.y & 15;
    int m0 = mt * 128;
    int nt = min(cnt[e], T_);
    if (m0 >= nt) return;
    int n0 = blockIdx.x * 64;
    int base = off[e];
    __shared__ bf16 As[128][40];
    __shared__ bf16 Bg[64][40];
    __shared__ bf16 Bu[64][40];
    __shared__ int  toks[128];
    int tid = threadIdx.x;
    if (tid < 128) {
        int m = m0 + tid;
        toks[tid] = ((m < nt) ? tok_list[e * T_ + m] : tok_list[e * T_]) & (T_ - 1);
    }
    __syncthreads();
    const float* w1e = w1 + (size_t)e * 2 * FF_ * D_;
    int wave = tid >> 6, lane = tid & 63, ml = lane & 15, quad = lane >> 4;
    int wm = wave * 32;
    f32x4 ag[2][4] = {}, au[2][4] = {};
    for (int kt = 0; kt < D_; kt += 32) {
        #pragma unroll
        for (int p = 0; p < 2; p++) {
            int ch = p * 256 + tid, row = ch >> 2, c8 = (ch & 3) << 3;
            *(uint4*)&As[row][c8] = *(const uint4*)&h2[(size_t)toks[row] * D_ + kt + c8];
        }
        #pragma unroll
        for (int p = 0; p < 2; p++) {
            int ch = p * 256 + tid, row = ch >> 3, c4 = (ch & 7) << 2;
            float4 vg = *(const float4*)&w1e[(size_t)(n0 + row) * D_ + kt + c4];
            float4 vu = *(const float4*)&w1e[(size_t)(FF_ + n0 + row) * D_ + kt + c4];
            uint2 wg; wg.x = pk2(vg.x, vg.y); wg.y = pk2(vg.z, vg.w);
            uint2 wu; wu.x = pk2(vu.x, vu.y); wu.y = pk2(vu.z, vu.w);
            *(uint2*)&Bg[row][c4] = wg;
            *(uint2*)&Bu[row][c4] = wu;
        }
        __syncthreads();
        bf16x8 a[2], bg[4], bu[4];
        #pragma unroll
        for (int i = 0; i < 2; i++) a[i] = *(const bf16x8*)&As[wm + i * 16 + ml][quad * 8];
        #pragma unroll
        for (int j = 0; j < 4; j++) {
            bg[j] = *(const bf16x8*)&Bg[j * 16 + ml][quad * 8];
            bu[j] = *(const bf16x8*)&Bu[j * 16 + ml][quad * 8];
        }
        #pragma unroll
        for (int i = 0; i < 2; i++)
            #pragma unroll
            for (int j = 0; j < 4; j++) {
                ag[i][j] = __builtin_amdgcn_mfma_f32_16x16x32_bf16(a[i], bg[j], ag[i][j], 0, 0, 0);
                au[i][j] = __builtin_amdgcn_mfma_f32_16x16x32_bf16(a[i], bu[j], au[i][j], 0, 0, 0);
            }
        __syncthreads();
    }
    #pragma unroll
    for (int i = 0; i < 2; i++)
        #pragma unroll
        for (int j = 0; j < 4; j++)
            #pragma unroll
            for (int r = 0; r < 4; r++) {
                int m = m0 + wm + i * 16 + quad * 4 + r;
                if (m < nt) {
                    float g = ag[i][j][r], u = au[i][j][r];
                    float a = g / (1.f + __expf(-g)) * u;
                    act[(size_t)(base + m) * FF_ + n0 + j * 16 + ml] = __float2bfloat16(a);
                }
            }
}

// ======== MoE w2 (MFMA), 64-token tiles, BK=64 — plain bf16 stores into ye ========
__global__ __launch_bounds__(256) void k_moe_w2_pre(const bf16* __restrict__ act,
                                                    const bf16* __restrict__ w2b,
                                                    const int* __restrict__ cnt,
                                                    const int* __restrict__ off,
                                                    const float* __restrict__ tok_w,
                                                    bf16* __restrict__ ye) {
    int e = blockIdx.y >> 5, mt = blockIdx.y & 31;   // T/64 = 32 m-tiles
    int m0 = mt * 64;
    int nt = min(cnt[e], T_);
    if (m0 >= nt) return;
    int n0 = blockIdx.x * 128;
    int base = off[e];
    __shared__ bf16 As[64 * 64];    // 8 KB
    __shared__ bf16 Bs[128 * 64];   // 16 KB
    int tid = threadIdx.x;
    int wave = tid >> 6, lane = tid & 63, ml = lane & 15, quad = lane >> 4;
    int wm = (wave >> 1) * 32, wn = (wave & 1) * 64;
    const bf16* w2e = w2b + (size_t)e * D_ * FF_;
    int r0 = tid >> 3, q0 = tid & 7;
    int ra1 = 32 + r0;
    int ca0 = (q0 ^ (r0 & 7)) << 3;
    int ca1 = (q0 ^ (ra1 & 7)) << 3;
    const bf16* sA0 = act + (size_t)(base + m0 + r0)  * FF_ + ca0;
    const bf16* sA1 = act + (size_t)(base + m0 + ra1) * FF_ + ca1;
    const bf16* sB[4];
    #pragma unroll
    for (int g = 0; g < 4; g++) {
        int rb = g * 32 + r0;
        int cb = (q0 ^ (rb & 7)) << 3;
        sB[g] = w2e + (size_t)(n0 + rb) * FF_ + cb;
    }
    int dstA0 = wave * 512, dstA1 = 2048 + wave * 512;
    int offA[2][2], offB[2][4];
    #pragma unroll
    for (int ks = 0; ks < 2; ks++) {
        int cq = ks * 4 + quad;
        #pragma unroll
        for (int i = 0; i < 2; i++) {
            int ra = wm + i * 16 + ml;
            offA[ks][i] = ra * 64 + ((cq ^ (ra & 7)) << 3);
        }
        #pragma unroll
        for (int j = 0; j < 4; j++) {
            int rb = wn + j * 16 + ml;
            offB[ks][j] = rb * 64 + ((cq ^ (rb & 7)) << 3);
        }
    }
    f32x4 acc[2][4] = {};
    for (int kt = 0; kt < FF_; kt += 64) {
        gload_lds16(sA0 + kt, As + dstA0);
        gload_lds16(sA1 + kt, As + dstA1);
        #pragma unroll
        for (int g = 0; g < 4; g++)
            gload_lds16(sB[g] + kt, Bs + g * 2048 + wave * 512);
        __syncthreads();
        #pragma unroll
        for (int ks = 0; ks < 2; ks++) {
            bf16x8 a[2], b[4];
            #pragma unroll
            for (int i = 0; i < 2; i++) a[i] = *(const bf16x8*)&As[offA[ks][i]];
            #pragma unroll
            for (int j = 0; j < 4; j++) b[j] = *(const bf16x8*)&Bs[offB[ks][j]];
            #pragma unroll
            for (int i = 0; i < 2; i++)
                #pragma unroll
                for (int j = 0; j < 4; j++)
                    acc[i][j] = __builtin_amdgcn_mfma_f32_16x16x32_bf16(a[i], b[j], acc[i][j], 0, 0, 0);
        }
        __syncthreads();
    }
    #pragma unroll
    for (int i = 0; i < 2; i++)
        #pragma unroll
        for (int r = 0; r < 4; r++) {
            int m = m0 + wm + i * 16 + quad * 4 + r;
            if (m < nt) {
                float wgt = tok_w[e * T_ + m];
                #pragma unroll
                for (int j = 0; j < 4; j++) {
                    int col = n0 + wn + j * 16 + ml;
                    ye[(size_t)(base + m) * D_ + col] = __float2bfloat16(wgt * acc[i][j][r]);
                }
            }
        }
}

// ---------------- combine: out0[t][d] = sum_k ye[off[e_k]+pos_k][d] ----------------
__global__ __launch_bounds__(256) void k_combine(const bf16* __restrict__ ye,
                                                 const int4* __restrict__ choice_idx,
                                                 const int4* __restrict__ pos4,
                                                 const int* __restrict__ off,
                                                 float* __restrict__ out0) {
    int t = blockIdx.x, tid = threadIdx.x;
    int4 ci = choice_idx[t];
    int4 ps = pos4[t];
    size_t rr0 = (size_t)(off[ci.x] + ps.x) * D_;
    size_t rr1 = (size_t)(off[ci.y] + ps.y) * D_;
    size_t rr2 = (size_t)(off[ci.z] + ps.z) * D_;
    size_t rr3 = (size_t)(off[ci.w] + ps.w) * D_;
    #pragma unroll
    for (int i = 0; i < 4; i++) {
        int d = tid + 256 * i;
        out0[(size_t)t * D_ + d] = b2f(ye[rr0 + d]) + b2f(ye[rr1 + d])
                                 + b2f(ye[rr2 + d]) + b2f(ye[rr3 + d]);
    }
}

// ---- fallback w2 (f32 weights, atomic combine) — round-7 verified ----
__global__ __launch_bounds__(256) void k_moe_w2(const bf16* __restrict__ act,
                                                const float* __restrict__ w2,
                                                const int* __restrict__ cnt,
                                                const int* __restrict__ off,
                                                const int* __restrict__ tok_list,
                                                const float* __restrict__ tok_w,
                                                float* __restrict__ out0) {
    int e = blockIdx.y >> 4, mt = blockIdx.y & 15;
    int m0 = mt * 128;
    int nt = min(cnt[e], T_);
    if (m0 >= nt) return;
    int n0 = blockIdx.x * 128;
    int base = off[e];
    __shared__ bf16 As[128][40];
    __shared__ bf16 Bs[128][40];
    int tid = threadIdx.x;
    int wave = tid >> 6, lane = tid & 63, ml = lane & 15, quad = lane >> 4;
    int wm = (wave >> 1) * 64, wn = (wave & 1) * 64;
    const float* w2e = w2 + (size_t)e * D_ * FF_;
    f32x4 acc[4][4] = {};
    for (int kt = 0; kt < FF_; kt += 32) {
        #pragma unroll
        for (int p = 0; p < 2; p++) {
            int ch = p * 256 + tid, row = ch >> 2, c8 = (ch & 3) << 3;
            uint4 v = make_uint4(0, 0, 0, 0);
            if (m0 + row < nt) v = *(const uint4*)&act[(size_t)(base + m0 + row) * FF_ + kt + c8];
            *(uint4*)&As[row][c8] = v;
        }
        #pragma unroll
        for (int p = 0; p < 4; p++) {
            int ch = p * 256 + tid, row = ch >> 3, c4 = (ch & 7) << 2;
            float4 v = *(const float4*)&w2e[(size_t)(n0 + row) * FF_ + kt + c4];
            uint2 w; w.x = pk2(v.x, v.y); w.y = pk2(v.z, v.w);
            *(uint2*)&Bs[row][c4] = w;
        }
        __syncthreads();
        bf16x8 a[4], b[4];
        #pragma unroll
        for (int i = 0; i < 4; i++) a[i] = *(const bf16x8*)&As[wm + i * 16 + ml][quad * 8];
        #pragma unroll
        for (int j = 0; j < 4; j++) b[j] = *(const bf16x8*)&Bs[wn + j * 16 + ml][quad * 8];
        #pragma unroll
        for (int i = 0; i < 4; i++)
            #pragma unroll
            for (int j = 0; j < 4; j++)
                acc[i][j] = __builtin_amdgcn_mfma_f32_16x16x32_bf16(a[i], b[j], acc[i][j], 0, 0, 0);
        __syncthreads();
    }
    #pragma unroll
    for (int i = 0; i < 4; i++)
        #pragma unroll
        for (int r = 0; r < 4; r++) {
            int m = m0 + wm + i * 16 + quad * 4 + r;
            if (m < nt) {
                int   tok = tok_list[e * T_ + m] & (T_ - 1);
                float wgt = tok_w[e * T_ + m];
                #pragma unroll
                for (int j = 0; j < 4; j++) {
                    int col = n0 + wn + j * 16 + ml;
                    atomicAdd(&out0[(size_t)tok * D_ + col], wgt * acc[i][j][r]);
                }
            }
        }
}

extern "C" void kernel_launch(void* const* d_in, const int* in_sizes, int n_in,
                              void* d_out, int out_size, void* d_ws, size_t ws_size,
                              hipStream_t stream) {
    const float* hidden     = (const float*)d_in[0];
    const float* residual   = (const float*)d_in[1];
    const float* op_norm_w  = (const float*)d_in[2];
    const float* ffn_norm_w = (const float*)d_in[3];
    const float* in_proj_w  = (const float*)d_in[4];
    const float* conv_w     = (const float*)d_in[5];
    const float* out_proj_w = (const float*)d_in[6];
    const float* gate_w     = (const float*)d_in[7];
    const float* gate_bias  = (const float*)d_in[8];
    const float* w1         = (const float*)d_in[9];
    const float* w2         = (const float*)d_in[10];

    // ---- base workspace (~32.6 MB) ----
    char* p = (char*)d_ws;
    int*    cnt        = (int*)p;        p += 256;   // cnt[0..15]; cnt[31] = done flag
    int*    off        = (int*)p;        p += 128;
    int*    tok_list   = (int*)p;        p += (size_t)E_ * T_ * 4;      // 128 KB
    float*  tok_w      = (float*)p;      p += (size_t)E_ * T_ * 4;      // 128 KB
    int4*   choice_idx = (int4*)p;       p += (size_t)T_ * 16;          // 32 KB
    float4* choice_wgt = (float4*)p;     p += (size_t)T_ * 16;          // 32 KB
    int4*   pos4       = (int4*)p;       p += (size_t)T_ * 16;          // 32 KB
    char*   regA       = p;              p += (size_t)T_ * D_ * 2 * 2;  // 8 MB
    char*   regB       = p;              p += (size_t)T_ * 3 * D_ * 4;  // 24 MB

    // pre-converted weight area (~64 MB, optional)
    const size_t n1 = (size_t)E_ * 2 * FF_ * D_;   // w1 elements
    const size_t n2 = (size_t)E_ * D_ * FF_;       // w2
    const size_t n3 = (size_t)3 * D_ * D_;         // in_proj
    const size_t n4 = (size_t)D_ * D_;             // out_proj
    bf16* w1b = (bf16*)p;  p += n1 * 2;
    bf16* w2b = (bf16*)p;  p += n2 * 2;
    bf16* iph = (bf16*)p;  p += n3 * 2;
    bf16* ipl = (bf16*)p;  p += n3 * 2;
    bf16* oph = (bf16*)p;  p += n4 * 2;
    bf16* opl = (bf16*)p;  p += n4 * 2;
    bool pre = ((size_t)(p - (char*)d_ws) <= ws_size);

    // regA: h1hi/h1lo -> cchi/cclo -> act (compact 8192 x FF bf16)
    bf16* h1hi = (bf16*)regA;
    bf16* h1lo = (bf16*)(regA + (size_t)T_ * D_ * 2);
    bf16* cchi = h1hi;
    bf16* cclo = h1lo;
    bf16* act  = (bf16*)regA;
    // regB: bcx f32 [0:24) -> y f32 [0:8) + h2b bf16 [16:20) -> ye bf16 [0:16)
    float* bcx = (float*)regB;
    float* y   = (float*)regB;
    bf16*  ye  = (bf16*)regB;                          // 8192 x 1024 bf16 = 16 MB
    bf16*  h2b = (bf16*)(regB + (size_t)T_ * D_ * 8);

    float* out0 = (float*)d_out;                    // MoE output [T,D] f32
    float* res  = out0 + (size_t)T_ * D_;           // residual slot

    if (pre) {
        int nq = (int)((n1 + n2 + n3 + n4) / 8 / 256);   // 14336 blocks (8 elems/thread)
        k_convert<<<nq, 256, 0, stream>>>(w1, w2, in_proj_w, out_proj_w,
                                          w1b, w2b, iph, ipl, oph, opl);
    }
    k_addnorm1z<<<T_, 256, 0, stream>>>(hidden, residual, op_norm_w, h1hi, h1lo, res, out0);
    if (pre)
        k_gemm_small<128><<<dim3(3 * D_ / 128, T_ / 64), 256, 0, stream>>>(
            h1hi, h1lo, iph, ipl, bcx, T_, 3 * D_, D_);
    else
        k_gemm_split<<<dim3(3 * D_ / 128, T_ / 128), 256, 0, stream>>>(
            h1hi, h1lo, in_proj_w, bcx, T_, 3 * D_, D_);
    k_conv2<<<T_, 256, 0, stream>>>(bcx, conv_w, cchi, cclo, cnt);
    if (pre)
        k_gemm_small<64><<<dim3(D_ / 64, T_ / 64), 256, 0, stream>>>(
            cchi, cclo, oph, opl, y, T_, D_, D_);
    else
        k_gemm_split<<<dim3(D_ / 128, T_ / 128), 256, 0, stream>>>(
            cchi, cclo, out_proj_w, y, T_, D_, D_);
    k_an2_gate<<<T_, 256, 0, stream>>>(y, res, ffn_norm_w, h2b, gate_w, gate_bias,
                                       choice_idx, choice_wgt);
    k_scatter2<<<E_, 256, 0, stream>>>(choice_idx, choice_wgt, cnt, tok_list, tok_w,
                                       (int*)pos4, off, &cnt[31]);
    if (pre) {
        k_moe_w1_pre<<<dim3(FF_ / 64, E_ * (T_ / 64)), 256, 0, stream>>>(
            h2b, w1b, cnt, off, tok_list, act);
        k_moe_w2_pre<<<dim3(D_ / 128, E_ * (T_ / 64)), 256, 0, stream>>>(
            act, w2b, cnt, off, tok_w, ye);
        k_combine<<<T_, 256, 0, stream>>>(ye, choice_idx, pos4, off, out0);
    } else {
        k_moe_w1<<<dim3(FF_ / 64, E_ * (T_ / 128)), 256, 0, stream>>>(
            h2b, w1, cnt, off, tok_list, act);
        k_moe_w2<<<dim3(D_ / 128, E_ * (T_ / 128)), 256, 0, stream>>>(
            act, w2, cnt, off, tok_list, tok_w, out0);
    }
}